// Round 8
// baseline (224.459 us; speedup 1.0000x reference)
//
#include <hip/hip_runtime.h>
#include <math.h>

#define BATCH 2
#define SEQ 2048
#define DMODEL 512
#define NH 8
#define HDIM 64
#define MTOT (BATCH * SEQ)              // 4096
#define QSIZE (BATCH * NH * SEQ * HDIM) // 2097152 elems per tensor
#define WSIZE (DMODEL * DMODEL)         // 262144 elems per weight

typedef __attribute__((ext_vector_type(8))) short bf16x8;
typedef __attribute__((ext_vector_type(16))) float f32x16;

__device__ inline unsigned short f2bf(float f) {
    union { float f; unsigned u; } v; v.f = f;
    unsigned u = v.u;
    u += 0x7fffu + ((u >> 16) & 1u);
    return (unsigned short)(u >> 16);
}
__device__ inline unsigned pack2(float lo, float hi) {
    return (unsigned)f2bf(lo) | ((unsigned)f2bf(hi) << 16);
}

// LDS row stride: 72 elems = 144 B (16B-aligned for b128; rotates banks by
// 4/row so 32-row fragment reads are conflict-free -- verified R7: 1.05e6
// conflicts, ~0.3% of cycles).
#define LSTR 72

// ws layout (bf16 elems):
#define WS_Q   ((size_t)0)
#define WS_K   ((size_t)QSIZE)
#define WS_V   (2 * (size_t)QSIZE)        // [B,H,HD,S] transposed
#define WS_CTX (3 * (size_t)QSIZE)
#define WS_WT  (4 * (size_t)QSIZE)        // 4 transposed weights (bf16 [n][k])
#define WS_ABF (4 * (size_t)QSIZE + 4 * (size_t)WSIZE)  // bf16 inputs q,k,v

// 32x32x16 bf16 MFMA layouts (m74/m101):
//   A[m][k]: m = lane&31, k = (lane>>5)*8 + j
//   B[k][n]: n = lane&31, k = (lane>>5)*8 + j
//   C/D:     col = lane&31, row = (reg&3) + 8*(reg>>2) + 4*(lane>>5)

// ---------------------------------------------------------------------------
// Kernel 0: fused prep. Blocks [0,1024): weight transpose+bf16 (4 x 256
// 32x32 tiles). Blocks [1024,4096): input fp32->bf16 (3 x 1024 chunks).
// ---------------------------------------------------------------------------
__global__ __launch_bounds__(256) void prep_kernel(
    const float* __restrict__ qin, const float* __restrict__ kin,
    const float* __restrict__ vin,
    const float* __restrict__ Wq, const float* __restrict__ Wk,
    const float* __restrict__ Wv, const float* __restrict__ Wo,
    unsigned short* __restrict__ ws)
{
    const int b = blockIdx.x;
    const int tid = threadIdx.x;

    if (b < 1024) {
        const int z = b >> 8, t = b & 255;
        const float* W = (z == 0) ? Wq : (z == 1) ? Wk : (z == 2) ? Wv : Wo;
        unsigned short* Wt = ws + WS_WT + (size_t)z * WSIZE;
        const int k0 = (t >> 4) * 32, n0 = (t & 15) * 32;

        __shared__ float T[32][33];
        {
            int r = tid >> 3, c = (tid & 7) * 4;
            float4 v = *(const float4*)&W[(size_t)(k0 + r) * DMODEL + n0 + c];
            T[r][c + 0] = v.x; T[r][c + 1] = v.y; T[r][c + 2] = v.z; T[r][c + 3] = v.w;
        }
        __syncthreads();
        {
            int n = tid >> 3, c = (tid & 7) * 4;
            uint2 o;
            o.x = pack2(T[c + 0][n], T[c + 1][n]);
            o.y = pack2(T[c + 2][n], T[c + 3][n]);
            *(uint2*)&Wt[(size_t)(n0 + n) * DMODEL + k0 + c] = o;
        }
    } else {
        const int idx = b - 1024;
        const int z = idx >> 10, blk = idx & 1023;
        const float* src = (z == 0) ? qin : (z == 1) ? kin : vin;
        unsigned short* dst = ws + WS_ABF + (size_t)z * QSIZE;
        const size_t i = ((size_t)blk * 256 + tid) * 8;
        float4 f0 = *(const float4*)(src + i);
        float4 f1 = *(const float4*)(src + i + 4);
        uint4 o;
        o.x = pack2(f0.x, f0.y); o.y = pack2(f0.z, f0.w);
        o.z = pack2(f1.x, f1.y); o.w = pack2(f1.z, f1.w);
        *(uint4*)(dst + i) = o;
    }
}

// ---------------------------------------------------------------------------
// Kernel 1: fused QKV projection, 32x32 MFMA. Tile 128 tokens x 64 dims,
// grid (8, 32, 3) = 768 blocks (3/CU). Wave owns 32 tokens x 64 dims.
// which<2 (Q,K): C cols = token, rows = dim  -> uint2 over hd, [B,H,S,HD].
// which==2 (V):  C cols = dim, rows = token  -> uint2 over s,  [B,H,HD,S].
// Q scaled 0.125.
// ---------------------------------------------------------------------------
__global__ __launch_bounds__(256) void qkv_mfma_kernel(
    unsigned short* __restrict__ ws,
    const float* __restrict__ bq, const float* __restrict__ bk,
    const float* __restrict__ bv)
{
    const int which = blockIdx.z;
    const unsigned short* A  = ws + WS_ABF + (size_t)which * QSIZE;
    const unsigned short* Wt = ws + WS_WT + (size_t)which * WSIZE;
    const float* bias = (which == 0) ? bq : (which == 1) ? bk : bv;
    unsigned short* out = ws + (size_t)which * QSIZE;

    __shared__ __align__(16) short As_[128][LSTR];  // tokens x k
    __shared__ __align__(16) short Bs_[64][LSTR];   // dims x k

    const int tid = threadIdx.x;
    const int lane = tid & 63, w = tid >> 6;
    const int ql = lane & 31, h = lane >> 5;
    const int m0 = blockIdx.y * 128, n0 = blockIdx.x * 64;

    const int ar = tid >> 1, ach = (tid & 1) * 32;  // As: row, 32-col half
    const int br = tid >> 2, bc = (tid & 3) * 16;   // Bs: row, 16-col quarter

    f32x16 acc[2];
    #pragma unroll
    for (int i = 0; i < 2; ++i)
        #pragma unroll
        for (int r = 0; r < 16; ++r) acc[i][r] = 0.f;

    for (int k0 = 0; k0 < DMODEL; k0 += 64) {
        __syncthreads();
        {
            const unsigned short* ap = A + (size_t)(m0 + ar) * DMODEL + k0 + ach;
            uint4 a0 = *(const uint4*)ap,        a1 = *(const uint4*)(ap + 8);
            uint4 a2 = *(const uint4*)(ap + 16), a3 = *(const uint4*)(ap + 24);
            *(uint4*)&As_[ar][ach]      = a0;
            *(uint4*)&As_[ar][ach + 8]  = a1;
            *(uint4*)&As_[ar][ach + 16] = a2;
            *(uint4*)&As_[ar][ach + 24] = a3;
        }
        {
            const unsigned short* wp = Wt + (size_t)(n0 + br) * DMODEL + k0 + bc;
            uint4 b0 = *(const uint4*)wp, b1 = *(const uint4*)(wp + 8);
            *(uint4*)&Bs_[br][bc]     = b0;
            *(uint4*)&Bs_[br][bc + 8] = b1;
        }
        __syncthreads();
        #pragma unroll
        for (int s = 0; s < 4; ++s) {
            bf16x8 at = *(const bf16x8*)&As_[w * 32 + ql][s * 16 + h * 8];
            bf16x8 bd[2];
            #pragma unroll
            for (int j = 0; j < 2; ++j)
                bd[j] = *(const bf16x8*)&Bs_[j * 32 + ql][s * 16 + h * 8];
            if (which < 2) {
                #pragma unroll
                for (int j = 0; j < 2; ++j)
                    acc[j] = __builtin_amdgcn_mfma_f32_32x32x16_bf16(bd[j], at, acc[j], 0, 0, 0);
            } else {
                #pragma unroll
                for (int j = 0; j < 2; ++j)
                    acc[j] = __builtin_amdgcn_mfma_f32_32x32x16_bf16(at, bd[j], acc[j], 0, 0, 0);
            }
        }
    }

    if (which < 2) {
        // C: rows = dim (2 32-tiles), cols = token (wave's 32).
        const float scale = (which == 0) ? 0.125f : 1.0f;
        const int tok = m0 + w * 32 + ql;
        const int b_ = tok >> 11, s_ = tok & (SEQ - 1);
        #pragma unroll
        for (int j = 0; j < 2; ++j) {
            #pragma unroll
            for (int g = 0; g < 4; ++g) {
                const int dim = n0 + j * 32 + 8 * g + 4 * h;
                const float4 b4 = *(const float4*)&bias[dim];
                const int h_ = dim >> 6, hd_ = dim & 63;
                uint2 o;
                o.x = pack2((acc[j][4 * g + 0] + b4.x) * scale,
                            (acc[j][4 * g + 1] + b4.y) * scale);
                o.y = pack2((acc[j][4 * g + 2] + b4.z) * scale,
                            (acc[j][4 * g + 3] + b4.w) * scale);
                *(uint2*)&out[((size_t)((b_ * NH + h_) * SEQ + s_)) * HDIM + hd_] = o;
            }
        }
    } else {
        // C: rows = token (runs of 4 consecutive s), cols = dim.
        #pragma unroll
        for (int j = 0; j < 2; ++j) {
            const int dim = n0 + j * 32 + ql;
            const int h_ = dim >> 6, hd_ = dim & 63;
            const float bv_ = bias[dim];
            #pragma unroll
            for (int g = 0; g < 4; ++g) {
                const int tok = m0 + w * 32 + 8 * g + 4 * h;
                const int b_ = tok >> 11, s_ = tok & (SEQ - 1);
                uint2 o;
                o.x = pack2(acc[j][4 * g + 0] + bv_, acc[j][4 * g + 1] + bv_);
                o.y = pack2(acc[j][4 * g + 2] + bv_, acc[j][4 * g + 3] + bv_);
                *(uint2*)&out[((size_t)((b_ * NH + h_) * HDIM + hd_)) * SEQ + s_] = o;
            }
        }
    }
}

// ---------------------------------------------------------------------------
// Kernel 2: flash attention, 32x32 MFMA, S^T form, KEY-SPLIT x2.
// grid (B*H=16, S/64=32) = 512 blocks (2/CU, 8 waves/CU). 4 waves:
// wave = (qb = w&1: 32-q subtile, s = w>>1: 1024-key strip). Each wave runs
// online softmax over its strip (16 ktiles of 64); strips merged exactly via
// log-sum-exp at the end (strip-1 state passed through LDS).
// ---------------------------------------------------------------------------
__global__ __launch_bounds__(256) void attn_mfma_kernel(
    const unsigned short* __restrict__ ws, unsigned short* __restrict__ ctx)
{
    const unsigned short* Q = ws + WS_Q;   // pre-scaled by 0.125
    const unsigned short* K = ws + WS_K;
    const unsigned short* V = ws + WS_V;   // [B,H,HD,S]

    __shared__ __align__(16) short Ks[2][64][LSTR];  // per-strip K[key][hd]
    __shared__ __align__(16) short Vt[2][64][LSTR];  // per-strip V^T[hd][key]
    __shared__ __align__(16) short Ps[2][64][LSTR];  // per-strip P[q][key]

    const int bh = blockIdx.x;
    const int q0 = blockIdx.y * 64;
    const int tid = threadIdx.x;
    const int lane = tid & 63, w = tid >> 6;
    const int ql = lane & 31, h = lane >> 5;
    const int qb = w & 1, s = w >> 1;
    const size_t base = (size_t)bh * SEQ * HDIM;
    const int q = q0 + qb * 32 + ql;

    bf16x8 qf[4];
    {
        const unsigned short* qr = Q + base + (size_t)q * HDIM;
        #pragma unroll
        for (int s4 = 0; s4 < 4; ++s4)
            qf[s4] = *(const bf16x8*)(qr + s4 * 16 + h * 8);
    }

    float m_prev = -1e30f, l_run = 0.f;
    f32x16 oacc[2];
    #pragma unroll
    for (int dt = 0; dt < 2; ++dt)
        #pragma unroll
        for (int r = 0; r < 16; ++r) oacc[dt][r] = 0.f;

    // staging: thread covers (sr, sc..sc+15) of all 4 tiles (2 strips x K,Vt)
    const int sr = tid >> 2, sc = (tid & 3) * 16;

    uint4 kpre[2][2], vpre[2][2];
    #pragma unroll
    for (int p = 0; p < 2; ++p) {
        const unsigned short* kp = K + base + (size_t)(p * 1024 + sr) * HDIM + sc;
        kpre[p][0] = *(const uint4*)kp;  kpre[p][1] = *(const uint4*)(kp + 8);
        const unsigned short* vp = V + base + (size_t)sr * SEQ + p * 1024 + sc;
        vpre[p][0] = *(const uint4*)vp;  vpre[p][1] = *(const uint4*)(vp + 8);
    }

    for (int kt = 0; kt < 1024; kt += 64) {
        __syncthreads();
        #pragma unroll
        for (int p = 0; p < 2; ++p) {
            *(uint4*)&Ks[p][sr][sc]     = kpre[p][0];
            *(uint4*)&Ks[p][sr][sc + 8] = kpre[p][1];
            *(uint4*)&Vt[p][sr][sc]     = vpre[p][0];
            *(uint4*)&Vt[p][sr][sc + 8] = vpre[p][1];
        }
        __syncthreads();
        {   // prefetch next ktile (clamped)
            const int ktn = (kt + 64 < 1024) ? kt + 64 : kt;
            #pragma unroll
            for (int p = 0; p < 2; ++p) {
                const unsigned short* kp = K + base + (size_t)(p * 1024 + ktn + sr) * HDIM + sc;
                kpre[p][0] = *(const uint4*)kp;  kpre[p][1] = *(const uint4*)(kp + 8);
                const unsigned short* vp = V + base + (size_t)sr * SEQ + p * 1024 + ktn + sc;
                vpre[p][0] = *(const uint4*)vp;  vpre[p][1] = *(const uint4*)(vp + 8);
            }
        }

        // ---- S^T = K.Q^T over this wave's strip ----
        f32x16 st[2];
        #pragma unroll
        for (int m = 0; m < 2; ++m) {
            f32x16 z;
            #pragma unroll
            for (int r = 0; r < 16; ++r) z[r] = 0.f;
            #pragma unroll
            for (int s4 = 0; s4 < 4; ++s4) {
                bf16x8 ka = *(const bf16x8*)&Ks[s][m * 32 + ql][s4 * 16 + h * 8];
                z = __builtin_amdgcn_mfma_f32_32x32x16_bf16(ka, qf[s4], z, 0, 0, 0);
            }
            st[m] = z;
        }

        // ---- online softmax (32 in-lane scores + partner lane^32) ----
        float tmax = st[0][0];
        #pragma unroll
        for (int m = 0; m < 2; ++m)
            #pragma unroll
            for (int r = 0; r < 16; ++r) tmax = fmaxf(tmax, st[m][r]);
        tmax = fmaxf(tmax, __shfl_xor(tmax, 32));

        const float mnew = fmaxf(m_prev, tmax);
        const float alpha = __expf(m_prev - mnew);
        float tsum = 0.f;
        #pragma unroll
        for (int m = 0; m < 2; ++m)
            #pragma unroll
            for (int r = 0; r < 16; ++r) {
                st[m][r] = __expf(st[m][r] - mnew);
                tsum += st[m][r];
            }
        tsum += __shfl_xor(tsum, 32);
        l_run = l_run * alpha + tsum;
        m_prev = mnew;
        #pragma unroll
        for (int dt = 0; dt < 2; ++dt)
            #pragma unroll
            for (int r = 0; r < 16; ++r) oacc[dt][r] *= alpha;

        // ---- write P[q][key] for this strip ----
        const int prow = qb * 32 + ql;
        #pragma unroll
        for (int m = 0; m < 2; ++m)
            #pragma unroll
            for (int g = 0; g < 4; ++g) {
                uint2 o;
                o.x = pack2(st[m][4 * g + 0], st[m][4 * g + 1]);
                o.y = pack2(st[m][4 * g + 2], st[m][4 * g + 3]);
                *(uint2*)&Ps[s][prow][m * 32 + 8 * g + 4 * h] = o;
            }
        // wave-private rows: lgkmcnt ordering suffices.

        // ---- O^T += V^T.P^T ----
        #pragma unroll
        for (int s4 = 0; s4 < 4; ++s4) {
            bf16x8 pf = *(const bf16x8*)&Ps[s][prow][s4 * 16 + h * 8];
            #pragma unroll
            for (int dt = 0; dt < 2; ++dt) {
                bf16x8 va = *(const bf16x8*)&Vt[s][dt * 32 + ql][s4 * 16 + h * 8];
                oacc[dt] = __builtin_amdgcn_mfma_f32_32x32x16_bf16(va, pf, oacc[dt], 0, 0, 0);
            }
        }
    }

    // ---- strip merge (exact log-sum-exp) + epilogue ----
    __syncthreads();   // all reads of Ks/Vt done; safe to overlay
    float* O1 = (float*)&Ks[0][0][0];   // [qb][d(64)][q(32)] f32 = 16 KB
    float* ML = (float*)&Vt[0][0][0];   // [qb][{m,l}][q(32)]

    if (s == 1) {
        #pragma unroll
        for (int dt = 0; dt < 2; ++dt)
            #pragma unroll
            for (int g = 0; g < 4; ++g)
                #pragma unroll
                for (int r = 0; r < 4; ++r) {
                    const int d = dt * 32 + 8 * g + 4 * h + r;
                    O1[(qb * 64 + d) * 32 + ql] = oacc[dt][4 * g + r];
                }
        if (h == 0) {
            ML[(qb * 2 + 0) * 32 + ql] = m_prev;
            ML[(qb * 2 + 1) * 32 + ql] = l_run;
        }
    }
    __syncthreads();

    if (s == 0) {
        const float m1 = ML[(qb * 2 + 0) * 32 + ql];
        const float l1 = ML[(qb * 2 + 1) * 32 + ql];
        const float mM = fmaxf(m_prev, m1);
        const float a0 = __expf(m_prev - mM);
        const float a1 = __expf(m1 - mM);
        const float linv = 1.f / (l_run * a0 + l1 * a1);

        const int b_ = bh >> 3, h_ = bh & 7;
        unsigned short* crow = ctx + ((size_t)(b_ * SEQ + q)) * DMODEL + h_ * HDIM;
        #pragma unroll
        for (int dt = 0; dt < 2; ++dt)
            #pragma unroll
            for (int g = 0; g < 4; ++g) {
                float v[4];
                #pragma unroll
                for (int r = 0; r < 4; ++r) {
                    const int d = dt * 32 + 8 * g + 4 * h + r;
                    v[r] = (oacc[dt][4 * g + r] * a0 + O1[(qb * 64 + d) * 32 + ql] * a1) * linv;
                }
                uint2 o;
                o.x = pack2(v[0], v[1]);
                o.y = pack2(v[2], v[3]);
                *(uint2*)&crow[dt * 32 + 8 * g + 4 * h] = o;
            }
    }
}

// ---------------------------------------------------------------------------
// Kernel 3: output projection, 32x32 MFMA, tile 64 tok x 64 dim,
// grid (8, 64) = 512 blocks. Wave owns one 32x32 C tile (rows = dim).
// fp32 epilogue, float4 stores.
// ---------------------------------------------------------------------------
__global__ __launch_bounds__(256) void out_proj_mfma_kernel(
    const unsigned short* __restrict__ ws, const float* __restrict__ bo,
    float* __restrict__ out)
{
    const unsigned short* ctx = ws + WS_CTX;
    const unsigned short* Wt  = ws + WS_WT + 3 * (size_t)WSIZE;

    __shared__ __align__(16) short As_[64][LSTR];  // tokens x k
    __shared__ __align__(16) short Bs_[64][LSTR];  // dims x k

    const int tid = threadIdx.x;
    const int lane = tid & 63, w = tid >> 6;
    const int ql = lane & 31, h = lane >> 5;
    const int m0 = blockIdx.y * 64, n0 = blockIdx.x * 64;
    const int dwv = (w & 1) * 32, twv = (w >> 1) * 32;

    const int ar = tid >> 2, ac = (tid & 3) * 16;

    f32x16 acc;
    #pragma unroll
    for (int r = 0; r < 16; ++r) acc[r] = 0.f;

    for (int k0 = 0; k0 < DMODEL; k0 += 64) {
        __syncthreads();
        {
            const unsigned short* ap = ctx + (size_t)(m0 + ar) * DMODEL + k0 + ac;
            uint4 c0 = *(const uint4*)ap, c1 = *(const uint4*)(ap + 8);
            *(uint4*)&As_[ar][ac]     = c0;
            *(uint4*)&As_[ar][ac + 8] = c1;
        }
        {
            const unsigned short* wp = Wt + (size_t)(n0 + ar) * DMODEL + k0 + ac;
            uint4 b0 = *(const uint4*)wp, b1 = *(const uint4*)(wp + 8);
            *(uint4*)&Bs_[ar][ac]     = b0;
            *(uint4*)&Bs_[ar][ac + 8] = b1;
        }
        __syncthreads();
        #pragma unroll
        for (int s = 0; s < 4; ++s) {
            bf16x8 a = *(const bf16x8*)&Bs_[dwv + ql][s * 16 + h * 8];
            bf16x8 b = *(const bf16x8*)&As_[twv + ql][s * 16 + h * 8];
            acc = __builtin_amdgcn_mfma_f32_32x32x16_bf16(a, b, acc, 0, 0, 0);
        }
    }

    const int tok = m0 + twv + ql;
    #pragma unroll
    for (int g = 0; g < 4; ++g) {
        const int dim = n0 + dwv + 8 * g + 4 * h;
        const float4 b4 = *(const float4*)&bo[dim];
        float4 o;
        o.x = acc[4 * g + 0] + b4.x;
        o.y = acc[4 * g + 1] + b4.y;
        o.z = acc[4 * g + 2] + b4.z;
        o.w = acc[4 * g + 3] + b4.w;
        *(float4*)&out[(size_t)tok * DMODEL + dim] = o;
    }
}

// ---------------------------------------------------------------------------
extern "C" void kernel_launch(void* const* d_in, const int* in_sizes, int n_in,
                              void* d_out, int out_size, void* d_ws, size_t ws_size,
                              hipStream_t stream)
{
    const float* qin = (const float*)d_in[0];
    const float* kin = (const float*)d_in[1];
    const float* vin = (const float*)d_in[2];
    const float* Wq  = (const float*)d_in[3];
    const float* bq  = (const float*)d_in[4];
    const float* Wk  = (const float*)d_in[5];
    const float* bk  = (const float*)d_in[6];
    const float* Wv  = (const float*)d_in[7];
    const float* bv  = (const float*)d_in[8];
    const float* Wo  = (const float*)d_in[9];
    const float* bo  = (const float*)d_in[10];

    unsigned short* ws = (unsigned short*)d_ws;
    float* out = (float*)d_out;

    prep_kernel<<<4096, 256, 0, stream>>>(qin, kin, vin, Wq, Wk, Wv, Wo, ws);

    dim3 gp(DMODEL / 64, MTOT / 128, 3);
    qkv_mfma_kernel<<<gp, 256, 0, stream>>>(ws, bq, bk, bv);

    dim3 ga(BATCH * NH, SEQ / 64);
    attn_mfma_kernel<<<ga, 256, 0, stream>>>(ws, ws + WS_CTX);

    dim3 go(DMODEL / 64, MTOT / 64);
    out_proj_mfma_kernel<<<go, 256, 0, stream>>>(ws, bo, out);
}

// Round 9
// 185.602 us; speedup vs baseline: 1.2094x; 1.2094x over previous
//
#include <hip/hip_runtime.h>
#include <math.h>

#define BATCH 2
#define SEQ 2048
#define DMODEL 512
#define NH 8
#define HDIM 64
#define MTOT (BATCH * SEQ)              // 4096
#define QSIZE (BATCH * NH * SEQ * HDIM) // 2097152 elems per tensor
#define WSIZE (DMODEL * DMODEL)         // 262144 elems per weight

typedef __attribute__((ext_vector_type(8))) short bf16x8;
typedef __attribute__((ext_vector_type(16))) float f32x16;

__device__ inline unsigned short f2bf(float f) {
    union { float f; unsigned u; } v; v.f = f;
    unsigned u = v.u;
    u += 0x7fffu + ((u >> 16) & 1u);
    return (unsigned short)(u >> 16);
}
__device__ inline unsigned pack2(float lo, float hi) {
    return (unsigned)f2bf(lo) | ((unsigned)f2bf(hi) << 16);
}
__device__ inline float bf2f(unsigned short u) {
    union { unsigned u; float f; } v; v.u = ((unsigned)u) << 16;
    return v.f;
}

// LDS row stride: 72 elems = 144 B (16B-aligned for b128; rotates banks by
// 4/row -> 32-row fragment reads conflict-free; verified R7 1.05e6 conflicts).
#define LSTR 72

// ws layout (bf16 elems):
#define WS_Q   ((size_t)0)
#define WS_K   ((size_t)QSIZE)
#define WS_V   (2 * (size_t)QSIZE)        // [B,H,HD,S] transposed
#define WS_ML  (3 * (size_t)QSIZE)        // fp32 (m,l) per (strip,bh,q): 512KB
#define WS_WT  (4 * (size_t)QSIZE)        // 4 transposed weights (bf16 [n][k])
#define WS_ABF (4 * (size_t)QSIZE + 4 * (size_t)WSIZE)  // bf16 inputs q,k,v;
                                          // after qkv consumes them, strips'
                                          // partial O (2 x QSIZE) overlay here.

// 32x32x16 bf16 MFMA layouts (m74/m101):
//   A[m][k]: m = lane&31, k = (lane>>5)*8 + j
//   B[k][n]: n = lane&31, k = (lane>>5)*8 + j
//   C/D:     col = lane&31, row = (reg&3) + 8*(reg>>2) + 4*(lane>>5)

// ---------------------------------------------------------------------------
// Kernel 0: fused prep. Blocks [0,1024): weight transpose+bf16.
// Blocks [1024,4096): input fp32->bf16.
// ---------------------------------------------------------------------------
__global__ __launch_bounds__(256) void prep_kernel(
    const float* __restrict__ qin, const float* __restrict__ kin,
    const float* __restrict__ vin,
    const float* __restrict__ Wq, const float* __restrict__ Wk,
    const float* __restrict__ Wv, const float* __restrict__ Wo,
    unsigned short* __restrict__ ws)
{
    const int b = blockIdx.x;
    const int tid = threadIdx.x;

    if (b < 1024) {
        const int z = b >> 8, t = b & 255;
        const float* W = (z == 0) ? Wq : (z == 1) ? Wk : (z == 2) ? Wv : Wo;
        unsigned short* Wt = ws + WS_WT + (size_t)z * WSIZE;
        const int k0 = (t >> 4) * 32, n0 = (t & 15) * 32;

        __shared__ float T[32][33];
        {
            int r = tid >> 3, c = (tid & 7) * 4;
            float4 v = *(const float4*)&W[(size_t)(k0 + r) * DMODEL + n0 + c];
            T[r][c + 0] = v.x; T[r][c + 1] = v.y; T[r][c + 2] = v.z; T[r][c + 3] = v.w;
        }
        __syncthreads();
        {
            int n = tid >> 3, c = (tid & 7) * 4;
            uint2 o;
            o.x = pack2(T[c + 0][n], T[c + 1][n]);
            o.y = pack2(T[c + 2][n], T[c + 3][n]);
            *(uint2*)&Wt[(size_t)(n0 + n) * DMODEL + k0 + c] = o;
        }
    } else {
        const int idx = b - 1024;
        const int z = idx >> 10, blk = idx & 1023;
        const float* src = (z == 0) ? qin : (z == 1) ? kin : vin;
        unsigned short* dst = ws + WS_ABF + (size_t)z * QSIZE;
        const size_t i = ((size_t)blk * 256 + tid) * 8;
        float4 f0 = *(const float4*)(src + i);
        float4 f1 = *(const float4*)(src + i + 4);
        uint4 o;
        o.x = pack2(f0.x, f0.y); o.y = pack2(f0.z, f0.w);
        o.z = pack2(f1.x, f1.y); o.w = pack2(f1.z, f1.w);
        *(uint4*)(dst + i) = o;
    }
}

// ---------------------------------------------------------------------------
// Kernel 1: fused QKV projection, 32x32 MFMA. Tile 128 tokens x 64 dims,
// grid (8, 32, 3) = 768 blocks (3/CU). [unchanged from R8 -- passed]
// ---------------------------------------------------------------------------
__global__ __launch_bounds__(256) void qkv_mfma_kernel(
    unsigned short* __restrict__ ws,
    const float* __restrict__ bq, const float* __restrict__ bk,
    const float* __restrict__ bv)
{
    const int which = blockIdx.z;
    const unsigned short* A  = ws + WS_ABF + (size_t)which * QSIZE;
    const unsigned short* Wt = ws + WS_WT + (size_t)which * WSIZE;
    const float* bias = (which == 0) ? bq : (which == 1) ? bk : bv;
    unsigned short* out = ws + (size_t)which * QSIZE;

    __shared__ __align__(16) short As_[128][LSTR];  // tokens x k
    __shared__ __align__(16) short Bs_[64][LSTR];   // dims x k

    const int tid = threadIdx.x;
    const int lane = tid & 63, w = tid >> 6;
    const int ql = lane & 31, h = lane >> 5;
    const int m0 = blockIdx.y * 128, n0 = blockIdx.x * 64;

    const int ar = tid >> 1, ach = (tid & 1) * 32;
    const int br = tid >> 2, bc = (tid & 3) * 16;

    f32x16 acc[2];
    #pragma unroll
    for (int i = 0; i < 2; ++i)
        #pragma unroll
        for (int r = 0; r < 16; ++r) acc[i][r] = 0.f;

    for (int k0 = 0; k0 < DMODEL; k0 += 64) {
        __syncthreads();
        {
            const unsigned short* ap = A + (size_t)(m0 + ar) * DMODEL + k0 + ach;
            uint4 a0 = *(const uint4*)ap,        a1 = *(const uint4*)(ap + 8);
            uint4 a2 = *(const uint4*)(ap + 16), a3 = *(const uint4*)(ap + 24);
            *(uint4*)&As_[ar][ach]      = a0;
            *(uint4*)&As_[ar][ach + 8]  = a1;
            *(uint4*)&As_[ar][ach + 16] = a2;
            *(uint4*)&As_[ar][ach + 24] = a3;
        }
        {
            const unsigned short* wp = Wt + (size_t)(n0 + br) * DMODEL + k0 + bc;
            uint4 b0 = *(const uint4*)wp, b1 = *(const uint4*)(wp + 8);
            *(uint4*)&Bs_[br][bc]     = b0;
            *(uint4*)&Bs_[br][bc + 8] = b1;
        }
        __syncthreads();
        #pragma unroll
        for (int s = 0; s < 4; ++s) {
            bf16x8 at = *(const bf16x8*)&As_[w * 32 + ql][s * 16 + h * 8];
            bf16x8 bd[2];
            #pragma unroll
            for (int j = 0; j < 2; ++j)
                bd[j] = *(const bf16x8*)&Bs_[j * 32 + ql][s * 16 + h * 8];
            if (which < 2) {
                #pragma unroll
                for (int j = 0; j < 2; ++j)
                    acc[j] = __builtin_amdgcn_mfma_f32_32x32x16_bf16(bd[j], at, acc[j], 0, 0, 0);
            } else {
                #pragma unroll
                for (int j = 0; j < 2; ++j)
                    acc[j] = __builtin_amdgcn_mfma_f32_32x32x16_bf16(at, bd[j], acc[j], 0, 0, 0);
            }
        }
    }

    if (which < 2) {
        const float scale = (which == 0) ? 0.125f : 1.0f;
        const int tok = m0 + w * 32 + ql;
        const int b_ = tok >> 11, s_ = tok & (SEQ - 1);
        #pragma unroll
        for (int j = 0; j < 2; ++j) {
            #pragma unroll
            for (int g = 0; g < 4; ++g) {
                const int dim = n0 + j * 32 + 8 * g + 4 * h;
                const float4 b4 = *(const float4*)&bias[dim];
                const int h_ = dim >> 6, hd_ = dim & 63;
                uint2 o;
                o.x = pack2((acc[j][4 * g + 0] + b4.x) * scale,
                            (acc[j][4 * g + 1] + b4.y) * scale);
                o.y = pack2((acc[j][4 * g + 2] + b4.z) * scale,
                            (acc[j][4 * g + 3] + b4.w) * scale);
                *(uint2*)&out[((size_t)((b_ * NH + h_) * SEQ + s_)) * HDIM + hd_] = o;
            }
        }
    } else {
        #pragma unroll
        for (int j = 0; j < 2; ++j) {
            const int dim = n0 + j * 32 + ql;
            const int h_ = dim >> 6, hd_ = dim & 63;
            const float bv_ = bias[dim];
            #pragma unroll
            for (int g = 0; g < 4; ++g) {
                const int tok = m0 + w * 32 + 8 * g + 4 * h;
                const int b_ = tok >> 11, s_ = tok & (SEQ - 1);
                uint2 o;
                o.x = pack2(acc[j][4 * g + 0] + bv_, acc[j][4 * g + 1] + bv_);
                o.y = pack2(acc[j][4 * g + 2] + bv_, acc[j][4 * g + 3] + bv_);
                *(uint2*)&out[((size_t)((b_ * NH + h_) * HDIM + hd_)) * SEQ + s_] = o;
            }
        }
    }
}

// ---------------------------------------------------------------------------
// Kernel 2: flash attention, 32x32 MFMA, S^T form, BLOCK-level key-split x2.
// grid (B*H=16, S/128=16, 2 strips) = 512 blocks (2/CU, 8 waves/CU).
// Per-block structure identical to R7 (36KB LDS, 4 waves x 32 q), strip of
// 1024 keys (16 ktiles). Writes UNNORMALIZED partial O (bf16, [B,S,D]) and
// per-q (m,l) fp32; merged exactly in out_proj's staging.
// ---------------------------------------------------------------------------
__global__ __launch_bounds__(256) void attn_mfma_kernel(
    unsigned short* __restrict__ ws)
{
    const unsigned short* Q = ws + WS_Q;   // pre-scaled by 0.125
    const unsigned short* K = ws + WS_K;
    const unsigned short* V = ws + WS_V;   // [B,H,HD,S]

    __shared__ __align__(16) short Ks[64][LSTR];   // K[key][hd]
    __shared__ __align__(16) short Vt[64][LSTR];   // V^T[hd][key]
    __shared__ __align__(16) short Ps[128][LSTR];  // P[q][key] (wave-private rows)

    const int bh = blockIdx.x;
    const int q0 = blockIdx.y * 128;
    const int strip = blockIdx.z;
    const int kbase = strip * 1024;
    const int tid = threadIdx.x;
    const int lane = tid & 63, w = tid >> 6;
    const int ql = lane & 31, h = lane >> 5;
    const size_t base = (size_t)bh * SEQ * HDIM;
    const int q = q0 + w * 32 + ql;

    bf16x8 qf[4];
    {
        const unsigned short* qr = Q + base + (size_t)q * HDIM;
        #pragma unroll
        for (int s4 = 0; s4 < 4; ++s4)
            qf[s4] = *(const bf16x8*)(qr + s4 * 16 + h * 8);
    }

    float m_prev = -1e30f, l_run = 0.f;
    f32x16 oacc[2];
    #pragma unroll
    for (int dt = 0; dt < 2; ++dt)
        #pragma unroll
        for (int r = 0; r < 16; ++r) oacc[dt][r] = 0.f;

    const int sr = tid >> 2, sc = (tid & 3) * 16;

    uint4 kpre[2], vpre[2];
    {
        const unsigned short* kp = K + base + (size_t)(kbase + sr) * HDIM + sc;
        kpre[0] = *(const uint4*)kp;  kpre[1] = *(const uint4*)(kp + 8);
        const unsigned short* vp = V + base + (size_t)sr * SEQ + kbase + sc;
        vpre[0] = *(const uint4*)vp;  vpre[1] = *(const uint4*)(vp + 8);
    }

    for (int kt = 0; kt < 1024; kt += 64) {
        __syncthreads();
        *(uint4*)&Ks[sr][sc]     = kpre[0];
        *(uint4*)&Ks[sr][sc + 8] = kpre[1];
        *(uint4*)&Vt[sr][sc]     = vpre[0];
        *(uint4*)&Vt[sr][sc + 8] = vpre[1];
        __syncthreads();
        {   // prefetch next ktile (clamped; redundant reload on last iter)
            const int ktn = (kt + 64 < 1024) ? kt + 64 : kt;
            const unsigned short* kp = K + base + (size_t)(kbase + ktn + sr) * HDIM + sc;
            kpre[0] = *(const uint4*)kp;  kpre[1] = *(const uint4*)(kp + 8);
            const unsigned short* vp = V + base + (size_t)sr * SEQ + kbase + ktn + sc;
            vpre[0] = *(const uint4*)vp;  vpre[1] = *(const uint4*)(vp + 8);
        }

        // ---- S^T = K.Q^T ----
        f32x16 st[2];
        #pragma unroll
        for (int m = 0; m < 2; ++m) {
            f32x16 z;
            #pragma unroll
            for (int r = 0; r < 16; ++r) z[r] = 0.f;
            #pragma unroll
            for (int s4 = 0; s4 < 4; ++s4) {
                bf16x8 ka = *(const bf16x8*)&Ks[m * 32 + ql][s4 * 16 + h * 8];
                z = __builtin_amdgcn_mfma_f32_32x32x16_bf16(ka, qf[s4], z, 0, 0, 0);
            }
            st[m] = z;
        }

        // ---- online softmax (32 in-lane scores + partner lane^32) ----
        float tmax = st[0][0];
        #pragma unroll
        for (int m = 0; m < 2; ++m)
            #pragma unroll
            for (int r = 0; r < 16; ++r) tmax = fmaxf(tmax, st[m][r]);
        tmax = fmaxf(tmax, __shfl_xor(tmax, 32));

        const float mnew = fmaxf(m_prev, tmax);
        const float alpha = __expf(m_prev - mnew);
        float tsum = 0.f;
        #pragma unroll
        for (int m = 0; m < 2; ++m)
            #pragma unroll
            for (int r = 0; r < 16; ++r) {
                st[m][r] = __expf(st[m][r] - mnew);
                tsum += st[m][r];
            }
        tsum += __shfl_xor(tsum, 32);
        l_run = l_run * alpha + tsum;
        m_prev = mnew;
        #pragma unroll
        for (int dt = 0; dt < 2; ++dt)
            #pragma unroll
            for (int r = 0; r < 16; ++r) oacc[dt][r] *= alpha;

        // ---- write P[q][key] ----
        const int prow = w * 32 + ql;
        #pragma unroll
        for (int m = 0; m < 2; ++m)
            #pragma unroll
            for (int g = 0; g < 4; ++g) {
                uint2 o;
                o.x = pack2(st[m][4 * g + 0], st[m][4 * g + 1]);
                o.y = pack2(st[m][4 * g + 2], st[m][4 * g + 3]);
                *(uint2*)&Ps[prow][m * 32 + 8 * g + 4 * h] = o;
            }
        // wave-private rows: lgkmcnt ordering suffices.

        // ---- O^T += V^T.P^T ----
        #pragma unroll
        for (int s4 = 0; s4 < 4; ++s4) {
            bf16x8 pf = *(const bf16x8*)&Ps[prow][s4 * 16 + h * 8];
            #pragma unroll
            for (int dt = 0; dt < 2; ++dt) {
                bf16x8 va = *(const bf16x8*)&Vt[dt * 32 + ql][s4 * 16 + h * 8];
                oacc[dt] = __builtin_amdgcn_mfma_f32_32x32x16_bf16(va, pf, oacc[dt], 0, 0, 0);
            }
        }
    }

    // ---- epilogue: UNNORMALIZED partial O (bf16) + (m,l) fp32 ----
    const int b_ = bh >> 3, h_ = bh & 7;
    unsigned short* orow = ws + WS_ABF + (size_t)strip * QSIZE
                         + ((size_t)(b_ * SEQ + q)) * DMODEL + h_ * HDIM;
    #pragma unroll
    for (int dt = 0; dt < 2; ++dt)
        #pragma unroll
        for (int g = 0; g < 4; ++g) {
            uint2 o;
            o.x = pack2(oacc[dt][4 * g + 0], oacc[dt][4 * g + 1]);
            o.y = pack2(oacc[dt][4 * g + 2], oacc[dt][4 * g + 3]);
            *(uint2*)&orow[dt * 32 + 8 * g + 4 * h] = o;
        }
    if (h == 0) {
        float* ML = (float*)(ws + WS_ML);
        const size_t idx = ((size_t)(strip * 16 + bh) * SEQ + q) * 2;
        ML[idx]     = m_prev;
        ML[idx + 1] = l_run;
    }
}

// ---------------------------------------------------------------------------
// Kernel 3: output projection with FUSED strip merge. A-staging reads the two
// partial-O tensors + (m,l), merges via exact log-sum-exp, converts to bf16
// in LDS. GEMM = R8's 64tok x 64dim 32x32-MFMA structure. grid (8, 64).
// ---------------------------------------------------------------------------
__global__ __launch_bounds__(256) void out_proj_mfma_kernel(
    const unsigned short* __restrict__ ws, const float* __restrict__ bo,
    float* __restrict__ out)
{
    const unsigned short* O0 = ws + WS_ABF;
    const unsigned short* O1 = ws + WS_ABF + QSIZE;
    const float* ML = (const float*)(ws + WS_ML);
    const unsigned short* Wt = ws + WS_WT + 3 * (size_t)WSIZE;

    __shared__ __align__(16) short As_[64][LSTR];  // merged ctx: tokens x k
    __shared__ __align__(16) short Bs_[64][LSTR];  // dims x k

    const int tid = threadIdx.x;
    const int lane = tid & 63, w = tid >> 6;
    const int ql = lane & 31, h = lane >> 5;
    const int m0 = blockIdx.y * 64, n0 = blockIdx.x * 64;
    const int dwv = (w & 1) * 32, twv = (w >> 1) * 32;

    const int ar = tid >> 2, ac = (tid & 3) * 16;

    const int tok = m0 + ar;
    const int b_ = tok >> 11, q_ = tok & (SEQ - 1);

    f32x16 acc;
    #pragma unroll
    for (int r = 0; r < 16; ++r) acc[r] = 0.f;

    for (int k0 = 0; k0 < DMODEL; k0 += 64) {
        __syncthreads();
        {   // ---- merge-stage A: ctx[tok][k0+ac .. +15] on the fly ----
            const int d0 = k0 + ac;
            const int h_ = d0 >> 6;               // head of this 16-col chunk
            const int bh = b_ * NH + h_;
            const size_t i0 = ((size_t)(0 * 16 + bh) * SEQ + q_) * 2;
            const size_t i1 = ((size_t)(1 * 16 + bh) * SEQ + q_) * 2;
            const float m0v = ML[i0], l0v = ML[i0 + 1];
            const float m1v = ML[i1], l1v = ML[i1 + 1];
            const float mM = fmaxf(m0v, m1v);
            float a0 = __expf(m0v - mM), a1 = __expf(m1v - mM);
            const float linv = 1.f / (a0 * l0v + a1 * l1v);
            a0 *= linv; a1 *= linv;

            union { uint4 v[2]; unsigned short s[16]; } p0, p1;
            const unsigned short* r0 = O0 + (size_t)tok * DMODEL + d0;
            const unsigned short* r1 = O1 + (size_t)tok * DMODEL + d0;
            p0.v[0] = *(const uint4*)r0; p0.v[1] = *(const uint4*)(r0 + 8);
            p1.v[0] = *(const uint4*)r1; p1.v[1] = *(const uint4*)(r1 + 8);
            unsigned short mg[16];
            #pragma unroll
            for (int i = 0; i < 16; ++i)
                mg[i] = f2bf(bf2f(p0.s[i]) * a0 + bf2f(p1.s[i]) * a1);
            *(uint4*)&As_[ar][ac]     = *(uint4*)&mg[0];
            *(uint4*)&As_[ar][ac + 8] = *(uint4*)&mg[8];
        }
        {
            const unsigned short* wp = Wt + (size_t)(n0 + ar) * DMODEL + k0 + ac;
            uint4 b0 = *(const uint4*)wp, b1 = *(const uint4*)(wp + 8);
            *(uint4*)&Bs_[ar][ac]     = b0;
            *(uint4*)&Bs_[ar][ac + 8] = b1;
        }
        __syncthreads();
        #pragma unroll
        for (int s = 0; s < 4; ++s) {
            bf16x8 a = *(const bf16x8*)&Bs_[dwv + ql][s * 16 + h * 8];
            bf16x8 b = *(const bf16x8*)&As_[twv + ql][s * 16 + h * 8];
            acc = __builtin_amdgcn_mfma_f32_32x32x16_bf16(a, b, acc, 0, 0, 0);
        }
    }

    const int tko = m0 + twv + ql;
    #pragma unroll
    for (int g = 0; g < 4; ++g) {
        const int dim = n0 + dwv + 8 * g + 4 * h;
        const float4 b4 = *(const float4*)&bo[dim];
        float4 o;
        o.x = acc[4 * g + 0] + b4.x;
        o.y = acc[4 * g + 1] + b4.y;
        o.z = acc[4 * g + 2] + b4.z;
        o.w = acc[4 * g + 3] + b4.w;
        *(float4*)&out[(size_t)tko * DMODEL + dim] = o;
    }
}

// ---------------------------------------------------------------------------
extern "C" void kernel_launch(void* const* d_in, const int* in_sizes, int n_in,
                              void* d_out, int out_size, void* d_ws, size_t ws_size,
                              hipStream_t stream)
{
    const float* qin = (const float*)d_in[0];
    const float* kin = (const float*)d_in[1];
    const float* vin = (const float*)d_in[2];
    const float* Wq  = (const float*)d_in[3];
    const float* bq  = (const float*)d_in[4];
    const float* Wk  = (const float*)d_in[5];
    const float* bk  = (const float*)d_in[6];
    const float* Wv  = (const float*)d_in[7];
    const float* bv  = (const float*)d_in[8];
    const float* Wo  = (const float*)d_in[9];
    const float* bo  = (const float*)d_in[10];

    unsigned short* ws = (unsigned short*)d_ws;
    float* out = (float*)d_out;

    prep_kernel<<<4096, 256, 0, stream>>>(qin, kin, vin, Wq, Wk, Wv, Wo, ws);

    dim3 gp(DMODEL / 64, MTOT / 128, 3);
    qkv_mfma_kernel<<<gp, 256, 0, stream>>>(ws, bq, bk, bv);

    dim3 ga(BATCH * NH, SEQ / 128, 2);
    attn_mfma_kernel<<<ga, 256, 0, stream>>>(ws);

    dim3 go(DMODEL / 64, MTOT / 64);
    out_proj_mfma_kernel<<<go, 256, 0, stream>>>(ws, bo, out);
}